// Round 21
// baseline (170.625 us; speedup 1.0000x reference)
//
#include <hip/hip_runtime.h>
#include <math.h>

#define NV   6890
#define NJ   24
#define NB   10
#define NPF  207
#define NCJ  19
#define BATCHN 1024
#define NC3  (NV*3)     // 20670
#define KTOT 224        // 207 pose + 10 beta + 1 template + 6 zero

#define OUT_JOINTS_OFF (BATCHN*NV*3)
#define OUT_RS_OFF     (OUT_JOINTS_OFF + BATCHN*NCJ*3)

// ws float offsets
#define WS_JS     0         // [24][33] f32
#define WS_EF     1024      // [1024][224] bf16
#define WS_AADJT  115712    // [1024][16][32] bf16
#define WS_DIRST  443392    // [216][42][512] bf16 frag-major
#define WS_WTB    2765824   // [216][32][32] bf16 weights frag-ready
#define WS_JRTB   2876416   // [216][2][16][32] bf16 jointreg frag-ready
#define WS_END    2987008   // floats

typedef __attribute__((ext_vector_type(8))) short short8;
typedef __attribute__((ext_vector_type(4))) float f32x4;

__device__ __forceinline__ unsigned short f2bf(float f) {
    unsigned u = __float_as_uint(f);
    unsigned r = u + 0x7FFFu + ((u >> 16) & 1u);   // RNE
    return (unsigned short)(r >> 16);
}
__device__ __forceinline__ float bf2f(unsigned short u) {
    return __uint_as_float((unsigned)u << 16);
}
__device__ __forceinline__ void async16(unsigned short* lds, const unsigned short* g) {
    __builtin_amdgcn_global_load_lds(
        (const __attribute__((address_space(1))) void*)g,
        (__attribute__((address_space(3))) void*)lds, 16, 0, 0);
}

// ------- Kernel AP: Jreg fold FIRST ∥ dirs transpose ∥ wt+jr pack ---------
// bx 0..23: Jreg fold | 24..1319: dirs transpose | 1320..1535: packs
__global__ __launch_bounds__(256) void smpl_kAP(
    const float* __restrict__ pdirs, const float* __restrict__ sdirs,
    unsigned short* __restrict__ dirsT,
    const float* __restrict__ jreg, const float* __restrict__ vtmpl,
    float* __restrict__ js,
    const float* __restrict__ jointreg, unsigned short* __restrict__ jrtb,
    const float* __restrict__ wts, unsigned short* __restrict__ wtb) {
    int bx = blockIdx.x, t = threadIdx.x;
    if (bx < NJ) {
        // Jreg fold (full f32 precision for the kinematic chain)
        int j = bx;
        float acc[33];
#pragma unroll
        for (int e = 0; e < 33; e++) acc[e] = 0.f;
        for (int v = t; v < NV; v += 256) {
            float w = jreg[j * NV + v];
#pragma unroll
            for (int k = 0; k < NB; k++) {
#pragma unroll
                for (int d = 0; d < 3; d++)
                    acc[k * 3 + d] += w * sdirs[(size_t)k * NC3 + v * 3 + d];
            }
#pragma unroll
            for (int d = 0; d < 3; d++) acc[30 + d] += w * vtmpl[v * 3 + d];
        }
#pragma unroll
        for (int e = 0; e < 33; e++) {
#pragma unroll
            for (int off = 32; off >= 1; off >>= 1) acc[e] += __shfl_xor(acc[e], off, 64);
        }
        __shared__ float red[4][33];
        int lane = t & 63, wv = t >> 6;
        if (lane == 0) {
#pragma unroll
            for (int e = 0; e < 33; e++) red[wv][e] = acc[e];
        }
        __syncthreads();
        if (t < 33) js[j * 33 + t] = red[0][t] + red[1][t] + red[2][t] + red[3][t];
        return;
    }
    if (bx < NJ + 216 * 6) {   // dirs -> frag-major bf16; row 217 = v_template
        int b2 = bx - NJ;
        int vt = b2 / 6, part = b2 - (b2 / 6) * 6;
        for (int g = part * 448 + t; g < part * 448 + 448; g += 256) {
            int frag = g >> 6, fo = g & 63;
            int ks = frag / 6, s = frag - ks * 6;
            int l15 = fo >> 2, lg = fo & 3;
            int gc = vt * 96 + s * 16 + l15;
            int k0 = ks * 32 + lg * 8;
            unsigned short pk[8];
#pragma unroll
            for (int i = 0; i < 8; i++) {
                int k = k0 + i;
                float val = 0.f;
                if (gc < NC3) {
                    if (k < NPF) val = pdirs[(size_t)k * NC3 + gc];
                    else if (k < NPF + NB) val = sdirs[(size_t)(k - NPF) * NC3 + gc];
                    else if (k == NPF + NB) val = vtmpl[gc];
                }
                pk[i] = f2bf(val);
            }
            *(short8*)(dirsT + (size_t)vt * 21504 + (size_t)g * 8) = *(const short8*)pk;
        }
        return;
    }
    // weights + jointreg -> frag-ready bf16 (one block per vtile)
    int vt = bx - (NJ + 216 * 6);
    for (int e = t; e < 1024; e += 256) {
        int vl = e >> 5, k = e & 31;
        int gv = vt * 32 + vl;
        float w = (k < NJ && gv < NV) ? wts[(size_t)gv * NJ + k] : 0.f;
        wtb[(size_t)vt * 1024 + e] = f2bf(w);
    }
    // jrtb[vt][h][j(16)][k(32)]: jr[h*16+j][vt*32+k]
    for (int e = t; e < 1024; e += 256) {
        int h = e >> 9, rem = e & 511, jj = rem >> 5, k = rem & 31;
        int j2 = h * 16 + jj;
        int gv = vt * 32 + k;
        float w = (j2 < NCJ && gv < NV) ? jointreg[(size_t)j2 * NV + gv] : 0.f;
        jrtb[(size_t)vt * 1024 + e] = f2bf(w);
    }
}

// ---------------- Kernel B: Rodrigues + chain + bf16 packs + joint zero ---
__global__ void smpl_kB(const float* __restrict__ theta, const float* __restrict__ beta_,
                        const float* __restrict__ js, float* __restrict__ outRs,
                        unsigned short* __restrict__ ef, unsigned short* __restrict__ aadjT,
                        float* __restrict__ outj) {
    int b = blockIdx.x;
    int t = threadIdx.x;  // 64
    __shared__ float Rl[NJ][9];
    __shared__ float Jl[NJ][3];
    __shared__ float Rw[NJ][12];

    if (t < 57) outj[(size_t)b * 57 + t] = 0.f;   // zero joints for kC atomics

    if (t < NJ) {
        int j = t;
        float tx = theta[b * 72 + j * 3 + 0];
        float ty = theta[b * 72 + j * 3 + 1];
        float tz = theta[b * 72 + j * 3 + 2];
        float ax = tx + 1e-8f, ay = ty + 1e-8f, az = tz + 1e-8f;
        float ang = sqrtf(ax * ax + ay * ay + az * az);
        float inv = 1.0f / ang;
        float rx = tx * inv, ry = ty * inv, rz = tz * inv;
        float s = sinf(ang), c = cosf(ang), t1 = 1.0f - c;
        float R[9];
        R[0] = 1.0f - t1 * (ry * ry + rz * rz);
        R[1] = -s * rz + t1 * rx * ry;
        R[2] =  s * ry + t1 * rx * rz;
        R[3] =  s * rz + t1 * rx * ry;
        R[4] = 1.0f - t1 * (rx * rx + rz * rz);
        R[5] = -s * rx + t1 * ry * rz;
        R[6] = -s * ry + t1 * rx * rz;
        R[7] =  s * rx + t1 * ry * rz;
        R[8] = 1.0f - t1 * (rx * rx + ry * ry);
#pragma unroll
        for (int e = 0; e < 9; e++) {
            Rl[j][e] = R[e];
            outRs[(size_t)b * 216 + j * 9 + e] = R[e];
        }
#pragma unroll
        for (int d = 0; d < 3; d++) {
            float accJ = js[j * 33 + 30 + d];
#pragma unroll
            for (int k = 0; k < NB; k++) accJ += beta_[b * NB + k] * js[j * 33 + k * 3 + d];
            Jl[j][d] = accJ;
        }
    }
    __syncthreads();
    // ef: [0..206] pose_feature, [207..216] beta, [217] = 1.0 (template row)
    for (int e = t; e < KTOT; e += 64) {
        float val;
        if (e < NPF) {
            int j = e / 9 + 1;
            int rc = e - (j - 1) * 9;
            val = Rl[j][rc] - ((rc == 0 || rc == 4 || rc == 8) ? 1.0f : 0.0f);
        } else if (e < NPF + NB) {
            val = beta_[b * NB + (e - NPF)];
        } else if (e == NPF + NB) {
            val = 1.0f;
        } else val = 0.f;
        ef[(size_t)b * KTOT + e] = f2bf(val);
    }
    if (t == 0) {
#pragma unroll
        for (int r = 0; r < 3; r++) {
            Rw[0][r * 4 + 0] =  Rl[0][r * 3 + 0];
            Rw[0][r * 4 + 1] = -Rl[0][r * 3 + 1];
            Rw[0][r * 4 + 2] = -Rl[0][r * 3 + 2];
            Rw[0][r * 4 + 3] =  Jl[0][r];
        }
        const int par[NJ] = {0,0,0,0,1,2,3,4,5,6,7,8,9,9,9,12,13,14,16,17,18,19,20,21};
#pragma unroll
        for (int i = 1; i < NJ; i++) {
            int p = par[i];
            float tr0 = Jl[i][0] - Jl[p][0];
            float tr1 = Jl[i][1] - Jl[p][1];
            float tr2 = Jl[i][2] - Jl[p][2];
#pragma unroll
            for (int r = 0; r < 3; r++) {
                float p0 = Rw[p][r * 4 + 0], p1 = Rw[p][r * 4 + 1], p2 = Rw[p][r * 4 + 2];
#pragma unroll
                for (int cc = 0; cc < 3; cc++)
                    Rw[i][r * 4 + cc] = p0 * Rl[i][0 + cc] + p1 * Rl[i][3 + cc] + p2 * Rl[i][6 + cc];
                Rw[i][r * 4 + 3] = p0 * tr0 + p1 * tr1 + p2 * tr2 + Rw[p][r * 4 + 3];
            }
        }
    }
    __syncthreads();
    // aadjT[b][n(16)][k(32)] bf16
    for (int i = t; i < 512; i += 64) {
        int n = i >> 5, k = i & 31;
        float v = 0.f;
        if (n < 12 && k < 24) {
            int r = n >> 2, cc = n & 3;
            if (cc < 3) v = Rw[k][n];
            else v = Rw[k][r * 4 + 3] - (Rw[k][r * 4 + 0] * Jl[k][0] + Rw[k][r * 4 + 1] * Jl[k][1] +
                                         Rw[k][r * 4 + 2] * Jl[k][2]);
        }
        aadjT[(size_t)b * 512 + i] = f2bf(v);
    }
}

// ------- Kernel C15: persistent async-LDS GEMM + T-blend + fused joints ---
// r19's kC11 plus: final verts written back (bf16) into vph during skinning,
// then 6 MFMAs/tile regress partial COCO joints; atomicAdd at block end.
__global__ __launch_bounds__(512, 2) void smpl_kC15(
    const unsigned short* __restrict__ dirsT, const unsigned short* __restrict__ wtb,
    const unsigned short* __restrict__ jrtb, const unsigned short* __restrict__ ef,
    const unsigned short* __restrict__ aadjT, float* __restrict__ outv,
    float* __restrict__ outj) {
    __shared__ __align__(16) unsigned short Bb[2][21504];   // 84KB frag-major dirs
    __shared__ __align__(16) unsigned short Wt[2][1024];    // 4KB weights
    __shared__ __align__(16) unsigned short vph[8][2176];   // 34KB per-wave verts

    int tid = threadIdx.x;
    int cg = blockIdx.x;                  // 0..31
    int bt = blockIdx.y;                  // 0..7
    int lane = tid & 63, wv = tid >> 6;   // 8 waves
    int l15 = lane & 15, lg = lane >> 4;
    int fo = l15 * 4 + lg;
    int nvt = (cg < 24) ? 7 : 6;          // 216 = 32*6 + 24
    int bb = bt * 128 + wv * 16;          // this wave's 16 batches

    // A-frags: once per block, reused across all vtiles
    const unsigned short* efb = ef + (size_t)(bb + l15) * KTOT;
    short8 av[7];
#pragma unroll
    for (int ks = 0; ks < 7; ks++) av[ks] = *(const short8*)(efb + ks * 32 + lg * 8);
    // aadjT-frags: once per block (tile-invariant)
    const short8* at0 = (const short8*)(aadjT + (size_t)bb * 512);
    short8 afr[16];
#pragma unroll
    for (int i = 0; i < 16; i++) afr[i] = at0[i * 64 + fo];

    // joint partial accumulators: row j = lg*4+r (+16h), col b = bb+l15
    f32x4 aj0[3], aj1[3];
#pragma unroll
    for (int d = 0; d < 3; d++) {
        aj0[d] = (f32x4){0.f, 0.f, 0.f, 0.f};
        aj1[d] = (f32x4){0.f, 0.f, 0.f, 0.f};
    }

    // stage vtile i into buffer p (pure linear async copies)
    auto stage = [&](int i, int p) {
        int vt = cg + i * 32;
        const unsigned short* bsrc = dirsT + (size_t)vt * 21504;
        for (int g0 = wv * 64; g0 < 2688; g0 += 512)
            async16(&Bb[p][(size_t)g0 * 8], bsrc + ((size_t)g0 + lane) * 8);
        if (wv < 2) {
            int g0 = wv * 64;
            async16(&Wt[p][g0 * 8], wtb + (size_t)vt * 1024 + ((size_t)g0 + lane) * 8);
        }
    };

    stage(0, 0);
    __syncthreads();   // vmcnt(0) drain + barrier: buffer 0 ready

    unsigned short* vp = vph[wv];

    for (int i = 0; i < nvt; i++) {
        int pc = i & 1;
        if (i + 1 < nvt) stage(i + 1, pc ^ 1);   // async, flies during compute
        int vt = cg + i * 32;

        short8 wf0 = *(const short8*)&Wt[pc][l15 * 32 + lg * 8];
        short8 wf1 = *(const short8*)&Wt[pc][(16 + l15) * 32 + lg * 8];
        const short8* jrp = (const short8*)(jrtb + (size_t)vt * 1024);
        short8 ja0 = jrp[fo];
        short8 ja1 = jrp[64 + fo];

        // ---- GEMM: 16 batches x 96 cols, K=224 (incl. template row) ----
        f32x4 acc[6];
#pragma unroll
        for (int s = 0; s < 6; s++) acc[s] = (f32x4){0.f, 0.f, 0.f, 0.f};
#pragma unroll
        for (int ks = 0; ks < 7; ks++) {
#pragma unroll
            for (int s = 0; s < 6; s++) {
                short8 bv = *(const short8*)&Bb[pc][((ks * 6 + s) << 9) + fo * 8];
                acc[s] = __builtin_amdgcn_mfma_f32_16x16x32_bf16(av[ks], bv, acc[s], 0, 0, 0);
            }
        }
        // ---- epilogue: vph = bf16(v_posed), wave-local ----
#pragma unroll
        for (int s = 0; s < 6; s++) {
            int col = s * 16 + l15;
            int v = col / 3, d = col - v * 3;
#pragma unroll
            for (int r = 0; r < 4; r++)
                vp[(v * 17 + lg * 4 + r) * 4 + d] = f2bf(acc[s][r]);
        }
        // ---- skinning: MFMA T-blend; final verts written back into vph ---
#pragma unroll
        for (int bl2 = 0; bl2 < 16; bl2++) {
            short8 af = afr[bl2];
            f32x4 z = (f32x4){0.f, 0.f, 0.f, 0.f};
            f32x4 t0 = __builtin_amdgcn_mfma_f32_16x16x32_bf16(af, wf0, z, 0, 0, 0);
            f32x4 t1 = __builtin_amdgcn_mfma_f32_16x16x32_bf16(af, wf1, z, 0, 0, 0);
            int b = bb + bl2;
            if (lg < 3) {
                int p = lg;
                int vv0 = l15, vv1 = 16 + l15;
                ushort4 xa = *(const ushort4*)&vp[(vv0 * 17 + bl2) * 4];
                ushort4 xb = *(const ushort4*)&vp[(vv1 * 17 + bl2) * 4];
                float o0 = fmaf(t0[0], bf2f(xa.x),
                           fmaf(t0[1], bf2f(xa.y), fmaf(t0[2], bf2f(xa.z), t0[3])));
                float o1 = fmaf(t1[0], bf2f(xb.x),
                           fmaf(t1[1], bf2f(xb.y), fmaf(t1[2], bf2f(xb.z), t1[3])));
                // in-place final-vert writeback (wave-lockstep: reads above
                // precede writes below for all lanes of this wave)
                vp[(vv0 * 17 + bl2) * 4 + p] = f2bf(o0);
                vp[(vv1 * 17 + bl2) * 4 + p] = f2bf(o1);
                int gv0 = vt * 32 + vv0, gv1 = vt * 32 + vv1;
                if (gv0 < NV) outv[(size_t)b * NC3 + gv0 * 3 + p] = o0;
                if (gv1 < NV) outv[(size_t)b * NC3 + gv1 * 3 + p] = o1;
            }
        }
        // ---- fused joints: aj += jrT(16x32) . verts(32x16) per dim ----
#pragma unroll
        for (int d = 0; d < 3; d++) {
            unsigned short bvv[8];
#pragma unroll
            for (int q = 0; q < 8; q++)
                bvv[q] = vp[((lg * 8 + q) * 17 + l15) * 4 + d];
            short8 bq = *(const short8*)bvv;
            aj0[d] = __builtin_amdgcn_mfma_f32_16x16x32_bf16(ja0, bq, aj0[d], 0, 0, 0);
            aj1[d] = __builtin_amdgcn_mfma_f32_16x16x32_bf16(ja1, bq, aj1[d], 0, 0, 0);
        }
        __syncthreads();   // reads of buf pc done; stage(i+1) writes drained
    }

    // ---- flush joint partials: C row j = lg*4+r (+16), col b = bb+l15 ----
    int bj = bb + l15;
#pragma unroll
    for (int r = 0; r < 4; r++) {
        int j0 = lg * 4 + r;
#pragma unroll
        for (int d = 0; d < 3; d++)
            atomicAdd(&outj[(size_t)bj * 57 + j0 * 3 + d], aj0[d][r]);
        int j1 = 16 + j0;
        if (j1 < NCJ) {
#pragma unroll
            for (int d = 0; d < 3; d++)
                atomicAdd(&outj[(size_t)bj * 57 + j1 * 3 + d], aj1[d][r]);
        }
    }
}

extern "C" void kernel_launch(void* const* d_in, const int* in_sizes, int n_in,
                              void* d_out, int out_size, void* d_ws, size_t ws_size,
                              hipStream_t stream) {
    (void)in_sizes; (void)n_in; (void)out_size; (void)ws_size;
    const float* beta       = (const float*)d_in[0];
    const float* theta      = (const float*)d_in[1];
    const float* v_template = (const float*)d_in[2];
    const float* shapedirs  = (const float*)d_in[3];
    const float* jreg       = (const float*)d_in[4];
    const float* posedirs   = (const float*)d_in[5];
    const float* jointreg   = (const float*)d_in[6];
    const float* weights    = (const float*)d_in[7];
    float* out = (float*)d_out;
    float* ws  = (float*)d_ws;
    unsigned short* ef    = (unsigned short*)(ws + WS_EF);
    unsigned short* aadjT = (unsigned short*)(ws + WS_AADJT);
    unsigned short* dirsT = (unsigned short*)(ws + WS_DIRST);
    unsigned short* wtb   = (unsigned short*)(ws + WS_WTB);
    unsigned short* jrtb  = (unsigned short*)(ws + WS_JRTB);

    smpl_kAP<<<NJ + 216 * 6 + 216, 256, 0, stream>>>(
        posedirs, shapedirs, dirsT, jreg, v_template, ws + WS_JS,
        jointreg, jrtb, weights, wtb);
    smpl_kB<<<BATCHN, 64, 0, stream>>>(theta, beta, ws + WS_JS, out + OUT_RS_OFF,
                                       ef, aadjT, out + OUT_JOINTS_OFF);
    dim3 gC(32, 8);
    smpl_kC15<<<gC, 512, 0, stream>>>(dirsT, wtb, jrtb, ef, aadjT, out,
                                      out + OUT_JOINTS_OFF);
}

// Round 22
// 114.258 us; speedup vs baseline: 1.4933x; 1.4933x over previous
//
#include <hip/hip_runtime.h>
#include <math.h>

#define NV   6890
#define NJ   24
#define NB   10
#define NPF  207
#define NCJ  19
#define BATCHN 1024
#define NC3  (NV*3)     // 20670
#define KTOT 224        // 207 pose + 10 beta + 1 template + 6 zero
#define NVP  6892       // jr row stride

#define OUT_JOINTS_OFF (BATCHN*NV*3)
#define OUT_RS_OFF     (OUT_JOINTS_OFF + BATCHN*NCJ*3)

// ws float offsets
#define WS_JS     0         // [24][33] f32
#define WS_EF     1024      // [1024][224] bf16
#define WS_AADJT  115712    // [1024][16][32] bf16
#define WS_JRB    377856    // [19][6892] bf16
#define WS_DIRST  443392    // [216][42][512] bf16 frag-major
#define WS_WTB    2765824   // [216][32][32] bf16 weights frag-ready
#define WS_END    2876416   // floats

typedef __attribute__((ext_vector_type(8))) short short8;
typedef __attribute__((ext_vector_type(4))) float f32x4;

__device__ __forceinline__ unsigned short f2bf(float f) {
    unsigned u = __float_as_uint(f);
    unsigned r = u + 0x7FFFu + ((u >> 16) & 1u);   // RNE
    return (unsigned short)(r >> 16);
}
__device__ __forceinline__ float bf2f(unsigned short u) {
    return __uint_as_float((unsigned)u << 16);
}
__device__ __forceinline__ void async16(unsigned short* lds, const unsigned short* g) {
    __builtin_amdgcn_global_load_lds(
        (const __attribute__((address_space(1))) void*)g,
        (__attribute__((address_space(3))) void*)lds, 16, 0, 0);
}

// ------- Kernel AP: Jreg fold FIRST (long pole overlaps the rest) ---------
__global__ __launch_bounds__(256) void smpl_kAP(
    const float* __restrict__ pdirs, const float* __restrict__ sdirs,
    unsigned short* __restrict__ dirsT,
    const float* __restrict__ jreg, const float* __restrict__ vtmpl,
    float* __restrict__ js,
    const float* __restrict__ jointreg, unsigned short* __restrict__ jrb,
    const float* __restrict__ wts, unsigned short* __restrict__ wtb) {
    int bx = blockIdx.x, t = threadIdx.x;
    if (bx < NJ) {
        // Jreg fold (full f32 precision for the kinematic chain)
        int j = bx;
        float acc[33];
#pragma unroll
        for (int e = 0; e < 33; e++) acc[e] = 0.f;
        for (int v = t; v < NV; v += 256) {
            float w = jreg[j * NV + v];
#pragma unroll
            for (int k = 0; k < NB; k++) {
#pragma unroll
                for (int d = 0; d < 3; d++)
                    acc[k * 3 + d] += w * sdirs[(size_t)k * NC3 + v * 3 + d];
            }
#pragma unroll
            for (int d = 0; d < 3; d++) acc[30 + d] += w * vtmpl[v * 3 + d];
        }
#pragma unroll
        for (int e = 0; e < 33; e++) {
#pragma unroll
            for (int off = 32; off >= 1; off >>= 1) acc[e] += __shfl_xor(acc[e], off, 64);
        }
        __shared__ float red[4][33];
        int lane = t & 63, wv = t >> 6;
        if (lane == 0) {
#pragma unroll
            for (int e = 0; e < 33; e++) red[wv][e] = acc[e];
        }
        __syncthreads();
        if (t < 33) js[j * 33 + t] = red[0][t] + red[1][t] + red[2][t] + red[3][t];
        return;
    }
    if (bx < NJ + 216 * 6) {   // dirs -> frag-major bf16; row 217 = v_template
        int b2 = bx - NJ;
        int vt = b2 / 6, part = b2 - (b2 / 6) * 6;
        for (int g = part * 448 + t; g < part * 448 + 448; g += 256) {
            int frag = g >> 6, fo = g & 63;
            int ks = frag / 6, s = frag - ks * 6;
            int l15 = fo >> 2, lg = fo & 3;
            int gc = vt * 96 + s * 16 + l15;
            int k0 = ks * 32 + lg * 8;
            unsigned short pk[8];
#pragma unroll
            for (int i = 0; i < 8; i++) {
                int k = k0 + i;
                float val = 0.f;
                if (gc < NC3) {
                    if (k < NPF) val = pdirs[(size_t)k * NC3 + gc];
                    else if (k < NPF + NB) val = sdirs[(size_t)(k - NPF) * NC3 + gc];
                    else if (k == NPF + NB) val = vtmpl[gc];
                }
                pk[i] = f2bf(val);
            }
            *(short8*)(dirsT + (size_t)vt * 21504 + (size_t)g * 8) = *(const short8*)pk;
        }
        return;
    }
    if (bx < NJ + 216 * 6 + NCJ) {   // jr -> bf16, padded rows
        int j = bx - (NJ + 216 * 6);
        for (int v = t; v < NVP; v += 256)
            jrb[(size_t)j * NVP + v] = (v < NV) ? f2bf(jointreg[(size_t)j * NV + v]) : 0;
        return;
    }
    // weights -> frag-ready bf16
    int vt = bx - (NJ + 216 * 6 + NCJ);
    for (int e = t; e < 1024; e += 256) {
        int vl = e >> 5, k = e & 31;
        int gv = vt * 32 + vl;
        float w = (k < NJ && gv < NV) ? wts[(size_t)gv * NJ + k] : 0.f;
        wtb[(size_t)vt * 1024 + e] = f2bf(w);
    }
}

// ---------------- Kernel B: Rodrigues + chain + bf16 packs ----------------
__global__ void smpl_kB(const float* __restrict__ theta, const float* __restrict__ beta_,
                        const float* __restrict__ js, float* __restrict__ outRs,
                        unsigned short* __restrict__ ef, unsigned short* __restrict__ aadjT) {
    int b = blockIdx.x;
    int t = threadIdx.x;  // 64
    __shared__ float Rl[NJ][9];
    __shared__ float Jl[NJ][3];
    __shared__ float Rw[NJ][12];

    if (t < NJ) {
        int j = t;
        float tx = theta[b * 72 + j * 3 + 0];
        float ty = theta[b * 72 + j * 3 + 1];
        float tz = theta[b * 72 + j * 3 + 2];
        float ax = tx + 1e-8f, ay = ty + 1e-8f, az = tz + 1e-8f;
        float ang = sqrtf(ax * ax + ay * ay + az * az);
        float inv = 1.0f / ang;
        float rx = tx * inv, ry = ty * inv, rz = tz * inv;
        float s = sinf(ang), c = cosf(ang), t1 = 1.0f - c;
        float R[9];
        R[0] = 1.0f - t1 * (ry * ry + rz * rz);
        R[1] = -s * rz + t1 * rx * ry;
        R[2] =  s * ry + t1 * rx * rz;
        R[3] =  s * rz + t1 * rx * ry;
        R[4] = 1.0f - t1 * (rx * rx + rz * rz);
        R[5] = -s * rx + t1 * ry * rz;
        R[6] = -s * ry + t1 * rx * rz;
        R[7] =  s * rx + t1 * ry * rz;
        R[8] = 1.0f - t1 * (rx * rx + ry * ry);
#pragma unroll
        for (int e = 0; e < 9; e++) {
            Rl[j][e] = R[e];
            outRs[(size_t)b * 216 + j * 9 + e] = R[e];
        }
#pragma unroll
        for (int d = 0; d < 3; d++) {
            float accJ = js[j * 33 + 30 + d];
#pragma unroll
            for (int k = 0; k < NB; k++) accJ += beta_[b * NB + k] * js[j * 33 + k * 3 + d];
            Jl[j][d] = accJ;
        }
    }
    __syncthreads();
    // ef: [0..206] pose_feature, [207..216] beta, [217] = 1.0 (template row)
    for (int e = t; e < KTOT; e += 64) {
        float val;
        if (e < NPF) {
            int j = e / 9 + 1;
            int rc = e - (j - 1) * 9;
            val = Rl[j][rc] - ((rc == 0 || rc == 4 || rc == 8) ? 1.0f : 0.0f);
        } else if (e < NPF + NB) {
            val = beta_[b * NB + (e - NPF)];
        } else if (e == NPF + NB) {
            val = 1.0f;
        } else val = 0.f;
        ef[(size_t)b * KTOT + e] = f2bf(val);
    }
    if (t == 0) {
#pragma unroll
        for (int r = 0; r < 3; r++) {
            Rw[0][r * 4 + 0] =  Rl[0][r * 3 + 0];
            Rw[0][r * 4 + 1] = -Rl[0][r * 3 + 1];
            Rw[0][r * 4 + 2] = -Rl[0][r * 3 + 2];
            Rw[0][r * 4 + 3] =  Jl[0][r];
        }
        const int par[NJ] = {0,0,0,0,1,2,3,4,5,6,7,8,9,9,9,12,13,14,16,17,18,19,20,21};
#pragma unroll
        for (int i = 1; i < NJ; i++) {
            int p = par[i];
            float tr0 = Jl[i][0] - Jl[p][0];
            float tr1 = Jl[i][1] - Jl[p][1];
            float tr2 = Jl[i][2] - Jl[p][2];
#pragma unroll
            for (int r = 0; r < 3; r++) {
                float p0 = Rw[p][r * 4 + 0], p1 = Rw[p][r * 4 + 1], p2 = Rw[p][r * 4 + 2];
#pragma unroll
                for (int cc = 0; cc < 3; cc++)
                    Rw[i][r * 4 + cc] = p0 * Rl[i][0 + cc] + p1 * Rl[i][3 + cc] + p2 * Rl[i][6 + cc];
                Rw[i][r * 4 + 3] = p0 * tr0 + p1 * tr1 + p2 * tr2 + Rw[p][r * 4 + 3];
            }
        }
    }
    __syncthreads();
    // aadjT[b][n(16)][k(32)] bf16
    for (int i = t; i < 512; i += 64) {
        int n = i >> 5, k = i & 31;
        float v = 0.f;
        if (n < 12 && k < 24) {
            int r = n >> 2, cc = n & 3;
            if (cc < 3) v = Rw[k][n];
            else v = Rw[k][r * 4 + 3] - (Rw[k][r * 4 + 0] * Jl[k][0] + Rw[k][r * 4 + 1] * Jl[k][1] +
                                         Rw[k][r * 4 + 2] * Jl[k][2]);
        }
        aadjT[(size_t)b * 512 + i] = f2bf(v);
    }
}

// ------- Kernel C11: persistent-block async-LDS GEMM + MFMA T-blend -------
// grid (32 colgroups, 8 btiles) = 256 blocks (1/CU); 512 thr / 8 waves.
// A-frags AND aadjT-frags register-resident for the whole block. v_template
// rides K-row 217 of the GEMM. Double-buffered async staging.
__global__ __launch_bounds__(512, 2) void smpl_kC11(
    const unsigned short* __restrict__ dirsT, const unsigned short* __restrict__ wtb,
    const unsigned short* __restrict__ ef, const unsigned short* __restrict__ aadjT,
    float* __restrict__ outv) {
    __shared__ __align__(16) unsigned short Bb[2][21504];   // 84KB frag-major dirs
    __shared__ __align__(16) unsigned short Wt[2][1024];    // 4KB weights
    __shared__ __align__(16) unsigned short vph[8][2176];   // 34KB per-wave v_posed

    int tid = threadIdx.x;
    int cg = blockIdx.x;                  // 0..31
    int bt = blockIdx.y;                  // 0..7
    int lane = tid & 63, wv = tid >> 6;   // 8 waves
    int l15 = lane & 15, lg = lane >> 4;
    int fo = l15 * 4 + lg;
    int nvt = (cg < 24) ? 7 : 6;          // 216 = 32*6 + 24
    int bb = bt * 128 + wv * 16;          // this wave's 16 batches

    // A-frags: once per block, reused across all vtiles
    const unsigned short* efb = ef + (size_t)(bb + l15) * KTOT;
    short8 av[7];
#pragma unroll
    for (int ks = 0; ks < 7; ks++) av[ks] = *(const short8*)(efb + ks * 32 + lg * 8);
    // aadjT-frags: once per block (tile-invariant); 64 VGPRs
    const short8* at0 = (const short8*)(aadjT + (size_t)bb * 512);
    short8 afr[16];
#pragma unroll
    for (int i = 0; i < 16; i++) afr[i] = at0[i * 64 + fo];

    // stage vtile i into buffer p (pure linear async copies)
    auto stage = [&](int i, int p) {
        int vt = cg + i * 32;
        const unsigned short* bsrc = dirsT + (size_t)vt * 21504;
        for (int g0 = wv * 64; g0 < 2688; g0 += 512)
            async16(&Bb[p][(size_t)g0 * 8], bsrc + ((size_t)g0 + lane) * 8);
        if (wv < 2) {
            int g0 = wv * 64;
            async16(&Wt[p][g0 * 8], wtb + (size_t)vt * 1024 + ((size_t)g0 + lane) * 8);
        }
    };

    stage(0, 0);
    __syncthreads();   // vmcnt(0) drain + barrier: buffer 0 ready

    unsigned short* vp = vph[wv];

    for (int i = 0; i < nvt; i++) {
        int pc = i & 1;
        if (i + 1 < nvt) stage(i + 1, pc ^ 1);   // async, flies during compute
        int vt = cg + i * 32;

        short8 wf0 = *(const short8*)&Wt[pc][l15 * 32 + lg * 8];
        short8 wf1 = *(const short8*)&Wt[pc][(16 + l15) * 32 + lg * 8];

        // ---- GEMM: 16 batches x 96 cols, K=224 (incl. template row) ----
        f32x4 acc[6];
#pragma unroll
        for (int s = 0; s < 6; s++) acc[s] = (f32x4){0.f, 0.f, 0.f, 0.f};
#pragma unroll
        for (int ks = 0; ks < 7; ks++) {
#pragma unroll
            for (int s = 0; s < 6; s++) {
                short8 bv = *(const short8*)&Bb[pc][((ks * 6 + s) << 9) + fo * 8];
                acc[s] = __builtin_amdgcn_mfma_f32_16x16x32_bf16(av[ks], bv, acc[s], 0, 0, 0);
            }
        }
        // ---- epilogue: vph = bf16(acc), wave-local ----
#pragma unroll
        for (int s = 0; s < 6; s++) {
            int col = s * 16 + l15;
            int v = col / 3, d = col - v * 3;
#pragma unroll
            for (int r = 0; r < 4; r++)
                vp[(v * 17 + lg * 4 + r) * 4 + d] = f2bf(acc[s][r]);
        }
        // ---- skinning: per-batch MFMA T-blend on register-resident afr ---
#pragma unroll
        for (int bl2 = 0; bl2 < 16; bl2++) {
            short8 af = afr[bl2];
            f32x4 z = (f32x4){0.f, 0.f, 0.f, 0.f};
            f32x4 t0 = __builtin_amdgcn_mfma_f32_16x16x32_bf16(af, wf0, z, 0, 0, 0);
            f32x4 t1 = __builtin_amdgcn_mfma_f32_16x16x32_bf16(af, wf1, z, 0, 0, 0);
            int b = bb + bl2;
            if (lg < 3) {
                int p = lg;
                {
                    int vv = l15;
                    ushort4 xv = *(const ushort4*)&vp[(vv * 17 + bl2) * 4];
                    float o = fmaf(t0[0], bf2f(xv.x),
                              fmaf(t0[1], bf2f(xv.y), fmaf(t0[2], bf2f(xv.z), t0[3])));
                    int gv = vt * 32 + vv;
                    if (gv < NV) outv[(size_t)b * NC3 + gv * 3 + p] = o;
                }
                {
                    int vv = 16 + l15;
                    ushort4 xv = *(const ushort4*)&vp[(vv * 17 + bl2) * 4];
                    float o = fmaf(t1[0], bf2f(xv.x),
                              fmaf(t1[1], bf2f(xv.y), fmaf(t1[2], bf2f(xv.z), t1[3])));
                    int gv = vt * 32 + vv;
                    if (gv < NV) outv[(size_t)b * NC3 + gv * 3 + p] = o;
                }
            }
        }
        __syncthreads();   // reads of buf pc done; stage(i+1) writes drained
    }
}

// ---------------- Kernel D: COCO joints, 4 verts/iter, bf16 jr ------------
__global__ __launch_bounds__(256) void smpl_kD(
    const float* __restrict__ verts, const unsigned short* __restrict__ jrb,
    float* __restrict__ outj) {
    int tid = threadIdx.x;
    int b = blockIdx.x;
    const float* vb = verts + (size_t)b * NC3;
    float acc[57];
#pragma unroll
    for (int e = 0; e < 57; e++) acc[e] = 0.f;

    for (int it = 0; it < 7; it++) {
        int g = it * 256 + tid;       // group of 4 verts; 1723 groups
        if (g < 1723) {
            int v = g * 4;
            const float* pa = vb + v * 3;
            float2 q0 = *(const float2*)(pa + 0);
            float2 q1 = *(const float2*)(pa + 2);
            float2 q2 = *(const float2*)(pa + 4);
            float2 q3 = *(const float2*)(pa + 6);
            float2 q4 = *(const float2*)(pa + 8);
            float2 q5 = *(const float2*)(pa + 10);
#pragma unroll
            for (int j = 0; j < NCJ; j++) {
                uint2 wp = *(const uint2*)(jrb + (size_t)j * NVP + v);
                float w0 = __uint_as_float((wp.x & 0xFFFFu) << 16);
                float w1 = __uint_as_float(wp.x & 0xFFFF0000u);
                float w2 = __uint_as_float((wp.y & 0xFFFFu) << 16);
                float w3 = __uint_as_float(wp.y & 0xFFFF0000u);
                acc[j * 3 + 0] += w0 * q0.x + w1 * q1.y + w2 * q3.x + w3 * q4.y;
                acc[j * 3 + 1] += w0 * q0.y + w1 * q2.x + w2 * q3.y + w3 * q5.x;
                acc[j * 3 + 2] += w0 * q1.x + w1 * q2.y + w2 * q4.x + w3 * q5.y;
            }
        }
    }
#pragma unroll
    for (int e = 0; e < 57; e++) {
#pragma unroll
        for (int off = 32; off >= 1; off >>= 1) acc[e] += __shfl_xor(acc[e], off, 64);
    }
    __shared__ float red[4][57];
    int lane = tid & 63, wv = tid >> 6;
    if (lane == 0) {
#pragma unroll
        for (int e = 0; e < 57; e++) red[wv][e] = acc[e];
    }
    __syncthreads();
    if (tid < 57)
        outj[(size_t)b * 57 + tid] = red[0][tid] + red[1][tid] + red[2][tid] + red[3][tid];
}

extern "C" void kernel_launch(void* const* d_in, const int* in_sizes, int n_in,
                              void* d_out, int out_size, void* d_ws, size_t ws_size,
                              hipStream_t stream) {
    (void)in_sizes; (void)n_in; (void)out_size; (void)ws_size;
    const float* beta       = (const float*)d_in[0];
    const float* theta      = (const float*)d_in[1];
    const float* v_template = (const float*)d_in[2];
    const float* shapedirs  = (const float*)d_in[3];
    const float* jreg       = (const float*)d_in[4];
    const float* posedirs   = (const float*)d_in[5];
    const float* jointreg   = (const float*)d_in[6];
    const float* weights    = (const float*)d_in[7];
    float* out = (float*)d_out;
    float* ws  = (float*)d_ws;
    unsigned short* ef    = (unsigned short*)(ws + WS_EF);
    unsigned short* aadjT = (unsigned short*)(ws + WS_AADJT);
    unsigned short* jrb   = (unsigned short*)(ws + WS_JRB);
    unsigned short* dirsT = (unsigned short*)(ws + WS_DIRST);
    unsigned short* wtb   = (unsigned short*)(ws + WS_WTB);

    smpl_kAP<<<NJ + 216 * 6 + NCJ + 216, 256, 0, stream>>>(
        posedirs, shapedirs, dirsT, jreg, v_template, ws + WS_JS,
        jointreg, jrb, weights, wtb);
    smpl_kB<<<BATCHN, 64, 0, stream>>>(theta, beta, ws + WS_JS, out + OUT_RS_OFF,
                                       ef, aadjT);
    dim3 gC(32, 8);
    smpl_kC11<<<gC, 512, 0, stream>>>(dirsT, wtb, ef, aadjT, out);
    smpl_kD<<<BATCHN, 256, 0, stream>>>(out, jrb, out + OUT_JOINTS_OFF);
}